// Round 1
// baseline (470.489 us; speedup 1.0000x reference)
//
#include <hip/hip_runtime.h>
#include <stdint.h>

#define D_IN 256
#define D_OUT 128
#define BUCKET_CAP 64

typedef __attribute__((ext_vector_type(8))) short bf16x8;
typedef __attribute__((ext_vector_type(4))) float f32x4;

__device__ __forceinline__ unsigned short f2bf(float f) {
  union { float f; uint32_t u; } v; v.f = f;
  uint32_t u = v.u;
  uint32_t r = (u + 0x7FFFu + ((u >> 16) & 1u)) >> 16;  // RNE
  return (unsigned short)r;
}

__global__ __launch_bounds__(256) void k_zero(int* __restrict__ p, int n) {
  int i = blockIdx.x * 256 + threadIdx.x;
  if (i < n) p[i] = 0;
}

// Histogram + bucket-bin in one pass: cnt[d] ends as indegree, bucket rows hold srcs.
__global__ __launch_bounds__(256) void k_hist_bin(const int* __restrict__ ei, int E,
                                                  int* __restrict__ cnt,
                                                  int* __restrict__ bkt) {
  int e = blockIdx.x * 256 + threadIdx.x;
  if (e >= E) return;
  int s = ei[e];        // src row of edge_index
  int d = ei[E + e];    // dst row
  int pos = atomicAdd(&cnt[d], 1);
  if (pos < BUCKET_CAP) bkt[d * BUCKET_CAP + pos] = s;
}

__global__ __launch_bounds__(256) void k_dinv(const int* __restrict__ cnt,
                                              float* __restrict__ dinv, int N) {
  int i = blockIdx.x * 256 + threadIdx.x;
  if (i < N) dinv[i] = rsqrtf(1.0f + (float)cnt[i]);  // +1 = self loop; deg always > 0
}

__global__ __launch_bounds__(256) void k_conv_x(const float4* __restrict__ x,
                                                ushort4* __restrict__ xb, int n4) {
  int i = blockIdx.x * 256 + threadIdx.x;
  if (i >= n4) return;
  float4 v = x[i];
  ushort4 o;
  o.x = f2bf(v.x); o.y = f2bf(v.y); o.z = f2bf(v.z); o.w = f2bf(v.w);
  xb[i] = o;
}

// W[k][n] (256x128 fp32) -> WT[n][k] (128x256 bf16) so B-fragments are 16B-contiguous loads.
__global__ __launch_bounds__(256) void k_conv_w(const float* __restrict__ W,
                                                unsigned short* __restrict__ wt) {
  int idx = blockIdx.x * 256 + threadIdx.x;  // 32768 = 128*256
  int n = idx >> 8;
  int k = idx & 255;
  wt[idx] = f2bf(W[k * D_OUT + n]);
}

// h'[r][c] = dinv[r] * sum_k x[r][k] W[k][c].  One wave per 16-row tile, 8 n-tiles of 16.
// MFMA 16x16x32 bf16: A[m=lane&15][k=q*8+j], B[k=q*8+j][n=lane&15], D col=lane&15 row=q*4+reg.
__global__ __launch_bounds__(256) void k_gemm(const unsigned short* __restrict__ xb,
                                              const unsigned short* __restrict__ wt,
                                              const float* __restrict__ dinv,
                                              float* __restrict__ hp, int N) {
  int wave = threadIdx.x >> 6;
  int lane = threadIdx.x & 63;
  int m = lane & 15;
  int q = lane >> 4;
  int r0 = blockIdx.x * 64 + wave * 16;
  if (r0 >= N) return;

  bf16x8 a[8];
  const unsigned short* xrow = xb + (size_t)(r0 + m) * D_IN + q * 8;
#pragma unroll
  for (int kt = 0; kt < 8; ++kt)
    a[kt] = *reinterpret_cast<const bf16x8*>(xrow + kt * 32);

  float4 dv = *reinterpret_cast<const float4*>(dinv + r0 + q * 4);
  float dvv[4] = {dv.x, dv.y, dv.z, dv.w};

#pragma unroll
  for (int nt = 0; nt < 8; ++nt) {
    f32x4 acc = {0.f, 0.f, 0.f, 0.f};
    const unsigned short* wrow = wt + (size_t)(nt * 16 + m) * D_IN + q * 8;
#pragma unroll
    for (int kt = 0; kt < 8; ++kt) {
      bf16x8 bv = *reinterpret_cast<const bf16x8*>(wrow + kt * 32);
      acc = __builtin_amdgcn_mfma_f32_16x16x32_bf16(a[kt], bv, acc, 0, 0, 0);
    }
#pragma unroll
    for (int r = 0; r < 4; ++r) {
      int row = r0 + q * 4 + r;
      hp[(size_t)row * D_OUT + nt * 16 + m] = acc[r] * dvv[r];
    }
  }
}

// One 128-thread half-block per node: gather-sum incoming h'[src] rows (coalesced, L3-hit),
// add self term, scale, bias, relu.  N assumed even (N=100000), grid = N/2.
__global__ __launch_bounds__(256) void k_agg(const float* __restrict__ hp,
                                             const int* __restrict__ bkt,
                                             const int* __restrict__ cnt,
                                             const float* __restrict__ dinv,
                                             const float* __restrict__ bias,
                                             float* __restrict__ out, int N) {
  __shared__ int s_src[2][BUCKET_CAP];
  int half = threadIdx.x >> 7;
  int lf = threadIdx.x & 127;
  int node = blockIdx.x * 2 + half;
  int c = cnt[node];
  if (c > BUCKET_CAP) c = BUCKET_CAP;
  if (lf < c) s_src[half][lf] = bkt[node * BUCKET_CAP + lf];
  __syncthreads();

  float acc = hp[(size_t)node * D_OUT + lf];  // self-loop term
  int e = 0;
  for (; e + 3 < c; e += 4) {  // 4 independent loads in flight
    int s0 = s_src[half][e];
    int s1 = s_src[half][e + 1];
    int s2 = s_src[half][e + 2];
    int s3 = s_src[half][e + 3];
    float v0 = hp[(size_t)s0 * D_OUT + lf];
    float v1 = hp[(size_t)s1 * D_OUT + lf];
    float v2 = hp[(size_t)s2 * D_OUT + lf];
    float v3 = hp[(size_t)s3 * D_OUT + lf];
    acc += (v0 + v1) + (v2 + v3);
  }
  for (; e < c; ++e)
    acc += hp[(size_t)s_src[half][e] * D_OUT + lf];

  float v = dinv[node] * acc + bias[lf];
  out[(size_t)node * D_OUT + lf] = v > 0.f ? v : 0.f;
}

extern "C" void kernel_launch(void* const* d_in, const int* in_sizes, int n_in,
                              void* d_out, int out_size, void* d_ws, size_t ws_size,
                              hipStream_t stream) {
  const float* x = (const float*)d_in[0];
  const int* ei = (const int*)d_in[1];
  const float* W = (const float*)d_in[2];
  const float* bias = (const float*)d_in[3];
  int N = in_sizes[0] / D_IN;
  int E = in_sizes[1] / 2;
  float* out = (float*)d_out;

  // Workspace carve-out (~129 MB): cnt | dinv | x_bf16 | W^T_bf16 | h' | buckets
  char* w = (char*)d_ws;
  size_t off = 0;
  auto alloc = [&](size_t bytes) -> void* {
    void* p = w + off;
    off = (off + bytes + 255) & ~(size_t)255;
    return p;
  };
  int* cnt = (int*)alloc((size_t)N * 4);
  float* dinv = (float*)alloc((size_t)N * 4);
  unsigned short* xb = (unsigned short*)alloc((size_t)N * D_IN * 2);
  unsigned short* wt = (unsigned short*)alloc((size_t)D_IN * D_OUT * 2);
  float* hp = (float*)alloc((size_t)N * D_OUT * 4);
  int* bkt = (int*)alloc((size_t)N * BUCKET_CAP * 4);
  (void)ws_size; (void)n_in; (void)out_size;

  k_zero<<<(N + 255) / 256, 256, 0, stream>>>(cnt, N);
  k_hist_bin<<<(E + 255) / 256, 256, 0, stream>>>(ei, E, cnt, bkt);
  k_dinv<<<(N + 255) / 256, 256, 0, stream>>>(cnt, dinv, N);
  int n4 = N * (D_IN / 4);
  k_conv_x<<<(n4 + 255) / 256, 256, 0, stream>>>((const float4*)x, (ushort4*)xb, n4);
  k_conv_w<<<(D_IN * D_OUT + 255) / 256, 256, 0, stream>>>(W, wt);
  k_gemm<<<(N + 63) / 64, 256, 0, stream>>>(xb, wt, dinv, hp, N);
  k_agg<<<N / 2, 256, 0, stream>>>(hp, bkt, cnt, dinv, bias, out, N);
}

// Round 2
// 357.140 us; speedup vs baseline: 1.3174x; 1.3174x over previous
//
#include <hip/hip_runtime.h>
#include <stdint.h>

#define D_IN 256
#define D_OUT 128
#define BUCKET_CAP 64

typedef __attribute__((ext_vector_type(8))) short bf16x8;
typedef __attribute__((ext_vector_type(4))) float f32x4;

__device__ __forceinline__ unsigned short f2bf(float f) {
  union { float f; uint32_t u; } v; v.f = f;
  uint32_t u = v.u;
  uint32_t r = (u + 0x7FFFu + ((u >> 16) & 1u)) >> 16;  // RNE
  return (unsigned short)r;
}

__device__ __forceinline__ float bfbits2f(uint32_t bits) {
  union { uint32_t u; float f; } v; v.u = bits;
  return v.f;
}

__global__ __launch_bounds__(256) void k_zero(int* __restrict__ p, int n) {
  int i = blockIdx.x * 256 + threadIdx.x;
  if (i < n) p[i] = 0;
}

// W[k][n] (256x128 fp32) -> WT[n][k] (128x256 bf16): B-fragments 16B-contiguous.
__global__ __launch_bounds__(256) void k_conv_w(const float* __restrict__ W,
                                                unsigned short* __restrict__ wt) {
  int idx = blockIdx.x * 256 + threadIdx.x;  // 32768 = 128*256
  int n = idx >> 8;
  int k = idx & 255;
  wt[idx] = f2bf(W[k * D_OUT + n]);
}

// One dispatch, two block kinds interleaved ~1:4 so latency-bound hist waves and
// MFMA/memory-bound gemm waves are co-resident (m114 co-scheduling).
//  gemm part: h[r][c] = sum_k x[r][k] W[k][c], fp32 x loaded directly, cvt->bf16
//             in-register, MFMA 16x16x32 bf16, h stored bf16 (UNscaled).
//  hist part: cnt[d]++ (atomic, returns pos), bkt[d][pos]=s.
__global__ __launch_bounds__(256) void k_fused(const float* __restrict__ x,
                                               const unsigned short* __restrict__ wt,
                                               unsigned short* __restrict__ hp,
                                               int N,
                                               const int* __restrict__ ei, int E,
                                               int* __restrict__ cnt,
                                               int* __restrict__ bkt,
                                               int Gg, int R) {
  int k = blockIdx.x;
  bool is_gemm = ((k % R) == 0) && ((k / R) < Gg);
  if (is_gemm) {
    int gid = k / R;
    int wave = threadIdx.x >> 6;
    int lane = threadIdx.x & 63;
    int m = lane & 15;
    int q = lane >> 4;
    int r0 = gid * 64 + wave * 16;
    if (r0 >= N) return;  // N % 16 == 0 -> no partial wave tiles

    // A fragments: load fp32 x rows, convert to bf16 in-register.
    bf16x8 a[8];
    const float* xrow = x + (size_t)(r0 + m) * D_IN + q * 8;
#pragma unroll
    for (int kt = 0; kt < 8; ++kt) {
      float4 u0 = *reinterpret_cast<const float4*>(xrow + kt * 32);
      float4 u1 = *reinterpret_cast<const float4*>(xrow + kt * 32 + 4);
      bf16x8 av;
      av[0] = (short)f2bf(u0.x); av[1] = (short)f2bf(u0.y);
      av[2] = (short)f2bf(u0.z); av[3] = (short)f2bf(u0.w);
      av[4] = (short)f2bf(u1.x); av[5] = (short)f2bf(u1.y);
      av[6] = (short)f2bf(u1.z); av[7] = (short)f2bf(u1.w);
      a[kt] = av;
    }

#pragma unroll
    for (int nt = 0; nt < 8; ++nt) {
      f32x4 acc = {0.f, 0.f, 0.f, 0.f};
      const unsigned short* wrow = wt + (size_t)(nt * 16 + m) * D_IN + q * 8;
#pragma unroll
      for (int kt = 0; kt < 8; ++kt) {
        bf16x8 bv = *reinterpret_cast<const bf16x8*>(wrow + kt * 32);
        acc = __builtin_amdgcn_mfma_f32_16x16x32_bf16(a[kt], bv, acc, 0, 0, 0);
      }
#pragma unroll
      for (int r = 0; r < 4; ++r) {
        int row = r0 + q * 4 + r;
        hp[(size_t)row * D_OUT + nt * 16 + m] = f2bf(acc[r]);
      }
    }
  } else {
    // hist block id = k minus #gemm-blocks with index < k
    int hid = k - min((k + R - 1) / R, Gg);
    int e = hid * 256 + threadIdx.x;
    if (e >= E) return;
    int s = ei[e];
    int d = ei[E + e];
    int pos = atomicAdd(&cnt[d], 1);
    if (pos < BUCKET_CAP) bkt[d * BUCKET_CAP + pos] = s;
  }
}

// One wave per node, 2 cols per lane (bf16x2 = 4B/lane gather, 256B/row).
// out[d] = relu( rs(d) * ( sum_s rs(s)*h[s] + rs(d)*h[d] ) + b ),  rs(i)=rsqrt(1+cnt[i])
__global__ __launch_bounds__(256) void k_agg(const unsigned short* __restrict__ hp,
                                             const int* __restrict__ bkt,
                                             const int* __restrict__ cnt,
                                             const float* __restrict__ bias,
                                             float* __restrict__ out, int N) {
  __shared__ int s_src[4][BUCKET_CAP];
  int wave = threadIdx.x >> 6;
  int lane = threadIdx.x & 63;
  int node = blockIdx.x * 4 + wave;  // N % 4 == 0
  int c_true = cnt[node];
  int c = c_true < BUCKET_CAP ? c_true : BUCKET_CAP;
  if (lane < c) s_src[wave][lane] = bkt[node * BUCKET_CAP + lane];
  __syncthreads();

  float rs_self = rsqrtf(1.0f + (float)c_true);
  const uint32_t* hrow_self =
      reinterpret_cast<const uint32_t*>(hp + (size_t)node * D_OUT) + lane;
  uint32_t us = *hrow_self;
  float acc0 = rs_self * bfbits2f(us << 16);
  float acc1 = rs_self * bfbits2f(us & 0xFFFF0000u);

  int e = 0;
  for (; e + 4 <= c; e += 4) {
    int s0 = s_src[wave][e];
    int s1 = s_src[wave][e + 1];
    int s2 = s_src[wave][e + 2];
    int s3 = s_src[wave][e + 3];
    uint32_t u0 = reinterpret_cast<const uint32_t*>(hp + (size_t)s0 * D_OUT)[lane];
    uint32_t u1 = reinterpret_cast<const uint32_t*>(hp + (size_t)s1 * D_OUT)[lane];
    uint32_t u2 = reinterpret_cast<const uint32_t*>(hp + (size_t)s2 * D_OUT)[lane];
    uint32_t u3 = reinterpret_cast<const uint32_t*>(hp + (size_t)s3 * D_OUT)[lane];
    int c0 = cnt[s0], c1 = cnt[s1], c2 = cnt[s2], c3 = cnt[s3];
    float r0 = rsqrtf(1.0f + (float)c0);
    float r1 = rsqrtf(1.0f + (float)c1);
    float r2 = rsqrtf(1.0f + (float)c2);
    float r3 = rsqrtf(1.0f + (float)c3);
    acc0 += r0 * bfbits2f(u0 << 16) + r1 * bfbits2f(u1 << 16) +
            r2 * bfbits2f(u2 << 16) + r3 * bfbits2f(u3 << 16);
    acc1 += r0 * bfbits2f(u0 & 0xFFFF0000u) + r1 * bfbits2f(u1 & 0xFFFF0000u) +
            r2 * bfbits2f(u2 & 0xFFFF0000u) + r3 * bfbits2f(u3 & 0xFFFF0000u);
  }
  for (; e < c; ++e) {
    int s = s_src[wave][e];
    uint32_t u = reinterpret_cast<const uint32_t*>(hp + (size_t)s * D_OUT)[lane];
    float r = rsqrtf(1.0f + (float)cnt[s]);
    acc0 += r * bfbits2f(u << 16);
    acc1 += r * bfbits2f(u & 0xFFFF0000u);
  }

  float2 bv = *reinterpret_cast<const float2*>(bias + 2 * lane);
  float o0 = rs_self * acc0 + bv.x;
  float o1 = rs_self * acc1 + bv.y;
  float2 ov;
  ov.x = o0 > 0.f ? o0 : 0.f;
  ov.y = o1 > 0.f ? o1 : 0.f;
  *reinterpret_cast<float2*>(out + (size_t)node * D_OUT + 2 * lane) = ov;
}

extern "C" void kernel_launch(void* const* d_in, const int* in_sizes, int n_in,
                              void* d_out, int out_size, void* d_ws, size_t ws_size,
                              hipStream_t stream) {
  const float* x = (const float*)d_in[0];
  const int* ei = (const int*)d_in[1];
  const float* W = (const float*)d_in[2];
  const float* bias = (const float*)d_in[3];
  int N = in_sizes[0] / D_IN;
  int E = in_sizes[1] / 2;
  float* out = (float*)d_out;

  // Workspace carve-out (~52 MB): cnt | W^T_bf16 | h_bf16 | buckets
  char* w = (char*)d_ws;
  size_t off = 0;
  auto alloc = [&](size_t bytes) -> void* {
    void* p = w + off;
    off = (off + bytes + 255) & ~(size_t)255;
    return p;
  };
  int* cnt = (int*)alloc((size_t)N * 4);
  unsigned short* wt = (unsigned short*)alloc((size_t)D_IN * D_OUT * 2);
  unsigned short* hp = (unsigned short*)alloc((size_t)N * D_OUT * 2);
  int* bkt = (int*)alloc((size_t)N * BUCKET_CAP * 4);
  (void)ws_size; (void)n_in; (void)out_size;

  int Gg = (N + 63) / 64;            // gemm blocks (64 rows each)
  int Gh = (E + 255) / 256;          // hist blocks (256 edges each)
  int grid = Gg + Gh;
  int R = (grid + Gg - 1) / Gg;      // interleave stride (~5)

  k_zero<<<(N + 255) / 256, 256, 0, stream>>>(cnt, N);
  k_conv_w<<<(D_IN * D_OUT + 255) / 256, 256, 0, stream>>>(W, wt);
  k_fused<<<grid, 256, 0, stream>>>(x, wt, hp, N, ei, E, cnt, bkt, Gg, R);
  k_agg<<<N / 4, 256, 0, stream>>>(hp, bkt, cnt, bias, out, N);
}